// Round 1
// baseline (3576.663 us; speedup 1.0000x reference)
//
#include <hip/hip_runtime.h>
#include <cstdint>
#include <cstddef>

// Problem constants: B=16, T=128, K=1024, D=768, KP=102
// Scan trick: u_t = exp(alpha_t - t*log(1024)) stays O(1); forward step is a
// plain matvec against expT=exp(transition) (symmetric => coalesced row reads).
// Viterbi stores alpha history and recomputes argmax along the path only.

// ---- workspace layout (float offsets) ----
#define OFF_EM   ((size_t)0)         // emission   2048*1024
#define OFF_TR   ((size_t)2097152)   // transition 1024*1024
#define OFF_EXPT ((size_t)3145728)   // expT       1024*1024
#define OFF_U    ((size_t)4194304)   // u_hist     128*16*1024
#define OFF_AV   ((size_t)6291456)   // av_hist    128*16*1024
#define OFF_UA   ((size_t)8388608)   // ua_hist    128*16*102
#define OFF_ETOP ((size_t)8597504)   // em_top     2048*102
#define OFF_ITOP ((size_t)8806400)   // top_idx    2048*102 (int)
#define OFF_RMAX ((size_t)9015296)   // row_max    2048
#define OFF_RLSE ((size_t)9017344)   // row_lse    2048
#define OFF_SMP  ((size_t)9019392)   // sm_pred    2048 (int)
// total 9021440 floats = 36.1 MB

// ---------------- GEMM: [x_emb; state] (3072x768) @ state^T -> 3072x1024 ----
__global__ __launch_bounds__(256) void gemm_kernel(
    const float* __restrict__ x, const float* __restrict__ stm,
    float* __restrict__ emission, float* __restrict__ transition,
    float* __restrict__ expT) {
  __shared__ float As[16][68];
  __shared__ float Bs[16][68];
  const int tid = threadIdx.x;
  const int tx = tid & 15, ty = tid >> 4;
  const int m0 = blockIdx.x * 64, n0 = blockIdx.y * 64;
  const int lr = tid >> 2;          // row within 64-tile
  const int lc = (tid & 3) << 2;    // k-col within 16-chunk
  float acc[4][4] = {};
  const float* aptr;
  {
    int gr = m0 + lr;
    aptr = (gr < 2048) ? (x + (size_t)gr * 768) : (stm + (size_t)(gr - 2048) * 768);
  }
  const float* bptr = stm + (size_t)(n0 + lr) * 768;
  for (int k0 = 0; k0 < 768; k0 += 16) {
    float4 a4 = *(const float4*)(aptr + k0 + lc);
    float4 b4 = *(const float4*)(bptr + k0 + lc);
    __syncthreads();
    As[lc + 0][lr] = a4.x; As[lc + 1][lr] = a4.y; As[lc + 2][lr] = a4.z; As[lc + 3][lr] = a4.w;
    Bs[lc + 0][lr] = b4.x; Bs[lc + 1][lr] = b4.y; Bs[lc + 2][lr] = b4.z; Bs[lc + 3][lr] = b4.w;
    __syncthreads();
#pragma unroll
    for (int kk = 0; kk < 16; ++kk) {
      float a[4], b[4];
#pragma unroll
      for (int q = 0; q < 4; ++q) a[q] = As[kk][ty * 4 + q];
#pragma unroll
      for (int q = 0; q < 4; ++q) b[q] = Bs[kk][tx * 4 + q];
#pragma unroll
      for (int i2 = 0; i2 < 4; ++i2)
#pragma unroll
        for (int j2 = 0; j2 < 4; ++j2) acc[i2][j2] += a[i2] * b[j2];
    }
  }
  const float rs = 0.03608439182435161f;  // 1/sqrt(768)
#pragma unroll
  for (int i2 = 0; i2 < 4; ++i2) {
    int r = m0 + ty * 4 + i2;
#pragma unroll
    for (int j2 = 0; j2 < 4; ++j2) {
      int c = n0 + tx * 4 + j2;
      float v = acc[i2][j2] * rs;
      if (r < 2048) {
        emission[(size_t)r * 1024 + c] = v;
      } else {
        size_t o = (size_t)(r - 2048) * 1024 + c;
        transition[o] = v;
        expT[o] = expf(v);
      }
    }
  }
}

// ---------------- per-row: bitonic full sort (desc, stable) -> top-102, max, lse, argmax
__global__ __launch_bounds__(256) void topk_kernel(
    const float* __restrict__ emission, float* __restrict__ em_top,
    int* __restrict__ top_idx, float* __restrict__ row_max,
    float* __restrict__ row_lse, int* __restrict__ sm_pred) {
  __shared__ float v[1024];
  __shared__ int ix[1024];
  __shared__ float rb[256];
  const int row = blockIdx.x;
  const int tid = threadIdx.x;
  const float* e = emission + (size_t)row * 1024;
  for (int p = tid; p < 1024; p += 256) { v[p] = e[p]; ix[p] = p; }
  __syncthreads();
  for (int k = 2; k <= 1024; k <<= 1) {
    for (int j = k >> 1; j > 0; j >>= 1) {
      for (int p = tid; p < 1024; p += 256) {
        int l = p ^ j;
        if (l > p) {
          float va = v[p], vb = v[l];
          int ia = ix[p], ib = ix[l];
          // total order: value desc, index asc (stable => jnp tie semantics)
          bool aBefore = (va > vb) || (va == vb && ia < ib);
          bool up = ((p & k) == 0);
          if (up ? !aBefore : aBefore) { v[p] = vb; v[l] = va; ix[p] = ib; ix[l] = ia; }
        }
      }
      __syncthreads();
    }
  }
  float mx = v[0];
  float s = 0.f;
  for (int p = tid; p < 1024; p += 256) s += expf(v[p] - mx);
  rb[tid] = s; __syncthreads();
  for (int w = 128; w > 0; w >>= 1) { if (tid < w) rb[tid] += rb[tid + w]; __syncthreads(); }
  if (tid == 0) {
    row_max[row] = mx;
    row_lse[row] = mx + logf(rb[0]);
    sm_pred[row] = ix[0];
  }
  for (int p = tid; p < 102; p += 256) {
    em_top[(size_t)row * 102 + p] = v[p];
    top_idx[(size_t)row * 102 + p] = ix[p];
  }
}

// ---------------- t=0 init of the three scans ----
__global__ __launch_bounds__(256) void init_kernel(
    const float* __restrict__ emission, const float* __restrict__ em_top,
    float* __restrict__ u_hist, float* __restrict__ av_hist,
    float* __restrict__ ua_hist) {
  const int b = blockIdx.x, tid = threadIdx.x;
  for (int k = tid; k < 1024; k += 256) {
    float e = emission[((size_t)b * 128) * 1024 + k];
    u_hist[(size_t)b * 1024 + k] = expf(e);   // alpha_0 = em, shift 0
    av_hist[(size_t)b * 1024 + k] = e;
  }
  for (int j = tid; j < 102; j += 256)
    ua_hist[(size_t)b * 102 + j] = expf(em_top[((size_t)b * 128) * 102 + j]);
}

// ---------------- one scan step (t in 1..127), fused roles by blockIdx ----
// blocks [0,128): forward-sum, 8 cols each; [128,256): viterbi, 8 cols each;
// [256,272): approx forward, one batch each.
__global__ __launch_bounds__(256) void step_kernel(
    int t, const float* __restrict__ emission,
    const float* __restrict__ transition, const float* __restrict__ expT,
    const float* __restrict__ em_top, const int* __restrict__ top_idx,
    float* __restrict__ u_hist, float* __restrict__ av_hist,
    float* __restrict__ ua_hist) {
  __shared__ float ps[128];
  __shared__ int sidxp[102];
  __shared__ int sidxc[102];
  __shared__ float sua[102];
  const int bid = blockIdx.x, tid = threadIdx.x;
  if (bid < 128) {
    // forward-sum: u_t[b][j] = (sum_i u[b][i]*expT[i][j]) * exp(em) / 1024
    const int jl = tid & 7, b = (tid >> 3) & 15, h = tid >> 7;
    const int j = bid * 8 + jl;
    const float* usrc = u_hist + (size_t)(t - 1) * 16384 + (size_t)b * 1024;
    const float* er = expT + (size_t)j * 1024;  // symmetric: row j == col j
    float acc = 0.f;
    const int i0 = h * 512;
    for (int i = i0; i < i0 + 512; i += 4) {
      float4 u4 = *(const float4*)(usrc + i);
      float4 e4 = *(const float4*)(er + i);
      acc += u4.x * e4.x + u4.y * e4.y + u4.z * e4.z + u4.w * e4.w;
    }
    if (h == 1) ps[tid - 128] = acc;
    __syncthreads();
    if (h == 0) {
      acc += ps[tid];
      float em = emission[((size_t)b * 128 + t) * 1024 + j];
      u_hist[(size_t)t * 16384 + (size_t)b * 1024 + j] = acc * expf(em) * (1.0f / 1024.0f);
    }
  } else if (bid < 256) {
    // viterbi: av_t[b][j] = max_i(av[b][i] + T[i][j]) + em  (exact, order-free)
    const int jl = tid & 7, b = (tid >> 3) & 15, h = tid >> 7;
    const int j = (bid - 128) * 8 + jl;
    const float* asrc = av_hist + (size_t)(t - 1) * 16384 + (size_t)b * 1024;
    const float* tr = transition + (size_t)j * 1024;  // symmetric
    float m = -3.0e38f;
    const int i0 = h * 512;
    for (int i = i0; i < i0 + 512; i += 4) {
      float4 a4 = *(const float4*)(asrc + i);
      float4 t4 = *(const float4*)(tr + i);
      m = fmaxf(m, fmaxf(fmaxf(a4.x + t4.x, a4.y + t4.y), fmaxf(a4.z + t4.z, a4.w + t4.w)));
    }
    if (h == 1) ps[tid - 128] = m;
    __syncthreads();
    if (h == 0) {
      m = fmaxf(m, ps[tid]);
      float em = emission[((size_t)b * 128 + t) * 1024 + j];
      av_hist[(size_t)t * 16384 + (size_t)b * 1024 + j] = m + em;
    }
  } else {
    // approx: trans_t[i][j] == transition[idx_{t-1}[i]][idx_t[j]] -> gather expT
    const int b = bid - 256;
    if (tid < 102) {
      sidxp[tid] = top_idx[((size_t)b * 128 + (t - 1)) * 102 + tid];
      sidxc[tid] = top_idx[((size_t)b * 128 + t) * 102 + tid];
      sua[tid] = ua_hist[(size_t)(t - 1) * 1632 + (size_t)b * 102 + tid];
    }
    __syncthreads();
    const int j = tid & 127, h = tid >> 7;
    float acc = 0.f;
    if (j < 102) {
      const int col = sidxc[j];
      for (int i = h * 51; i < h * 51 + 51; ++i)
        acc += sua[i] * expT[(size_t)sidxp[i] * 1024 + col];
    }
    if (h == 1 && j < 102) ps[j] = acc;
    __syncthreads();
    if (h == 0 && j < 102) {
      acc += ps[j];
      float em = em_top[((size_t)b * 128 + t) * 102 + j];
      ua_hist[(size_t)t * 1632 + (size_t)b * 102 + j] = acc * expf(em) * (1.0f / 102.0f);
    }
  }
}

// ---------------- viterbi backtrace: recompute argmax along path only ----
__global__ __launch_bounds__(256) void backtrace_kernel(
    const float* __restrict__ av_hist, const float* __restrict__ transition,
    const int* __restrict__ y_lens, float* __restrict__ out_crf) {
  __shared__ float swv[4];
  __shared__ int swi[4];
  __shared__ int scur;
  const int b = blockIdx.x, tid = threadIdx.x;
  const int tb = y_lens[b] - 1;
  for (int t = tb + 1 + tid; t < 128; t += 256) out_crf[(size_t)b * 128 + t] = 0.f;
  // last_state = first-argmax of av_hist[tb][b][:]
  {
    const float* al = av_hist + (size_t)tb * 16384 + (size_t)b * 1024;
    float bv = -3.0e38f; int bi = 0x7fffffff;
    for (int i = tid; i < 1024; i += 256) {
      float val = al[i];
      if (val > bv || (val == bv && i < bi)) { bv = val; bi = i; }
    }
    for (int off = 32; off > 0; off >>= 1) {
      float ov = __shfl_xor(bv, off);
      int oi = __shfl_xor(bi, off);
      if (ov > bv || (ov == bv && oi < bi)) { bv = ov; bi = oi; }
    }
    if ((tid & 63) == 0) { swv[tid >> 6] = bv; swi[tid >> 6] = bi; }
    __syncthreads();
    if (tid == 0) {
      for (int q = 1; q < 4; ++q)
        if (swv[q] > bv || (swv[q] == bv && swi[q] < bi)) { bv = swv[q]; bi = swi[q]; }
      out_crf[(size_t)b * 128 + tb] = (float)bi;
      scur = bi;
    }
  }
  __syncthreads();
  int s = scur;
  for (int t = tb - 1; t >= 0; --t) {
    const float* al = av_hist + (size_t)t * 16384 + (size_t)b * 1024;
    const float* tr = transition + (size_t)s * 1024;  // column s == row s
    float bv = -3.0e38f; int bi = 0x7fffffff;
    for (int i = tid; i < 1024; i += 256) {
      float val = al[i] + tr[i];
      if (val > bv || (val == bv && i < bi)) { bv = val; bi = i; }
    }
    for (int off = 32; off > 0; off >>= 1) {
      float ov = __shfl_xor(bv, off);
      int oi = __shfl_xor(bi, off);
      if (ov > bv || (ov == bv && oi < bi)) { bv = ov; bi = oi; }
    }
    if ((tid & 63) == 0) { swv[tid >> 6] = bv; swi[tid >> 6] = bi; }
    __syncthreads();
    if (tid == 0) {
      for (int q = 1; q < 4; ++q)
        if (swv[q] > bv || (swv[q] == bv && swi[q] < bi)) { bv = swv[q]; bi = swi[q]; }
      out_crf[(size_t)b * 128 + t] = (float)bi;
      scur = bi;
    }
    __syncthreads();
    s = scur;
  }
}

// ---------------- scalars & metrics ----
__device__ __forceinline__ float blk_sum(float v, float* rb, int tid) {
  rb[tid] = v; __syncthreads();
  for (int w = 128; w > 0; w >>= 1) { if (tid < w) rb[tid] += rb[tid + w]; __syncthreads(); }
  float r = rb[0]; __syncthreads();
  return r;
}

__global__ __launch_bounds__(256) void finalize_kernel(
    const float* __restrict__ emission, const float* __restrict__ transition,
    const float* __restrict__ u_hist, const float* __restrict__ ua_hist,
    const float* __restrict__ row_max, const float* __restrict__ row_lse,
    const int* __restrict__ sm_pred, const int* __restrict__ y,
    const int* __restrict__ y_lens, float* __restrict__ d_out) {
  __shared__ float rb[256];
  __shared__ float sZ[16], sZa[16], sLogy[16];
  const int tid = threadIdx.x;
  const float* out_crf = d_out + 1;
  for (int b = 0; b < 16; ++b) {
    const int tb = y_lens[b] - 1;
    float p = 0.f;
    for (int i = tid; i < 1024; i += 256) p += u_hist[((size_t)tb * 16 + b) * 1024 + i];
    p = blk_sum(p, rb, tid);
    if (tid == 0) sZ[b] = logf(p) + (float)tb * 6.931471805599453f;  // ln(1024)
    float q = 0.f;
    for (int i = tid; i < 102; i += 256) q += ua_hist[((size_t)tb * 16 + b) * 102 + i];
    q = blk_sum(q, rb, tid);
    if (tid == 0) sZa[b] = logf(q) + (float)tb * 4.624972813284271f;  // ln(102)
  }
  if (tid < 16) sLogy[tid] = 0.f;
  __syncthreads();
  float a_local = 0, a_maxp = 0, c_sup = 0, c_pred = 0, c_ov = 0, c_match = 0;
  float s_predc = 0, s_ov = 0, s_match = 0;
  for (int r = tid; r < 2048; r += 256) {
    const int b = r >> 7, t = r & 127;
    const int L = y_lens[b];
    if (t < L) {
      const int yv = y[r];
      const float em_y = emission[(size_t)r * 1024 + yv];
      const float lse = row_lse[r];
      a_local += em_y - lse;
      a_maxp += expf(row_max[r] - lse);
      float term = em_y;
      if (t < L - 1) term += transition[(size_t)yv * 1024 + y[r + 1]];
      atomicAdd(&sLogy[b], term);
      const float ypos = (yv > 0) ? 1.f : 0.f;
      c_sup += ypos;
      const int cs = (int)out_crf[r];
      c_pred += (cs > 0) ? 1.f : 0.f;
      c_ov += ((cs > 0) && (yv > 0)) ? 1.f : 0.f;
      c_match += (cs == yv) ? 1.f : 0.f;
      const int ss = sm_pred[r];
      s_predc += (ss > 0) ? 1.f : 0.f;
      s_ov += ((ss > 0) && (yv > 0)) ? 1.f : 0.f;
      s_match += (ss == yv) ? 1.f : 0.f;
    }
  }
  __syncthreads();
  a_local = blk_sum(a_local, rb, tid);
  a_maxp = blk_sum(a_maxp, rb, tid);
  c_sup = blk_sum(c_sup, rb, tid);
  c_pred = blk_sum(c_pred, rb, tid);
  c_ov = blk_sum(c_ov, rb, tid);
  c_match = blk_sum(c_match, rb, tid);
  s_predc = blk_sum(s_predc, rb, tid);
  s_ov = blk_sum(s_ov, rb, tid);
  s_match = blk_sum(s_match, rb, tid);
  if (tid == 0) {
    float tl = 0.f;
    for (int b = 0; b < 16; ++b) tl += (float)y_lens[b];
    float mZ = 0, mZa = 0, dE = 0, dA = 0;
    for (int b = 0; b < 16; ++b) {
      mZ += sZ[b]; mZa += sZa[b];
      dE += sLogy[b] - sZ[b];
      dA += sLogy[b] - sZa[b];
    }
    mZ *= (1.f / 16.f); mZa *= (1.f / 16.f);
    const float sle = -dE * (1.f / 16.f);
    const float sla = -dA * (1.f / 16.f);
    const float slocal = a_local / tl;
    const float maxp = a_maxp / tl;
    const float loss = sla + 0.1f * slocal;
    const float crf_acc = c_match / tl;
    const float crf_prec = (c_pred > 0.f) ? (c_ov / fmaxf(c_pred, 1.f)) : 0.f;
    const float crf_recl = c_ov / fmaxf(c_sup, 1.f);
    const float crf_f1 = (crf_prec > 0.f)
        ? (2.f * crf_prec * crf_recl / fmaxf(crf_prec + crf_recl, 1e-12f)) : 0.f;
    const float sm_acc = s_match / tl;
    const float sm_prec = (s_predc > 0.f) ? (s_ov / fmaxf(s_predc, 1.f)) : 0.f;
    const float sm_recl = s_ov / fmaxf(c_sup, 1.f);
    const float sm_f1 = (sm_prec > 0.f)
        ? (2.f * sm_prec * sm_recl / fmaxf(sm_prec + sm_recl, 1e-12f)) : 0.f;
    d_out[0] = loss;
    d_out[2049] = mZ;
    d_out[2050] = mZa;
    d_out[2051] = sle;
    d_out[2052] = slocal;
    d_out[2053] = maxp;
    d_out[2054] = crf_acc;
    d_out[2055] = crf_f1;
    d_out[2056] = sm_acc;
    d_out[2057] = sm_f1;
  }
}

extern "C" void kernel_launch(void* const* d_in, const int* in_sizes, int n_in,
                              void* d_out, int out_size, void* d_ws, size_t ws_size,
                              hipStream_t stream) {
  const float* x = (const float*)d_in[0];    // x_emb (16,128,768)
  const float* stm = (const float*)d_in[1];  // state_matrix (1024,768)
  const int* y = (const int*)d_in[2];        // (16,128)
  const int* yl = (const int*)d_in[3];       // (16,)
  float* out = (float*)d_out;
  float* ws = (float*)d_ws;

  float* emission = ws + OFF_EM;
  float* transition = ws + OFF_TR;
  float* expT = ws + OFF_EXPT;
  float* u_hist = ws + OFF_U;
  float* av_hist = ws + OFF_AV;
  float* ua_hist = ws + OFF_UA;
  float* em_top = ws + OFF_ETOP;
  int* top_idx = (int*)(ws + OFF_ITOP);
  float* row_max = ws + OFF_RMAX;
  float* row_lse = ws + OFF_RLSE;
  int* sm_pred = (int*)(ws + OFF_SMP);

  gemm_kernel<<<dim3(48, 16), 256, 0, stream>>>(x, stm, emission, transition, expT);
  topk_kernel<<<2048, 256, 0, stream>>>(emission, em_top, top_idx, row_max, row_lse, sm_pred);
  init_kernel<<<16, 256, 0, stream>>>(emission, em_top, u_hist, av_hist, ua_hist);
  for (int t = 1; t < 128; ++t)
    step_kernel<<<272, 256, 0, stream>>>(t, emission, transition, expT, em_top,
                                         top_idx, u_hist, av_hist, ua_hist);
  backtrace_kernel<<<16, 256, 0, stream>>>(av_hist, transition, yl, out + 1);
  finalize_kernel<<<1, 256, 0, stream>>>(emission, transition, u_hist, ua_hist,
                                         row_max, row_lse, sm_pred, y, yl, out);
}